// Round 1
// baseline (787.986 us; speedup 1.0000x reference)
//
#include <hip/hip_runtime.h>

#define D 128
#define GEMM_ROWS 32

// ---------------- GEMM: h = x @ W ----------------
// Block: 256 threads, 32 rows x 128 cols per block.
// W (64KB) + x-tile (16KB) in LDS; each thread computes a 4x4 micro-tile.
__global__ __launch_bounds__(256) void gemm_kernel(const float* __restrict__ x,
                                                   const float* __restrict__ w,
                                                   float* __restrict__ h, int n) {
    __shared__ float wlds[D * D];          // 64 KB
    __shared__ float xlds[GEMM_ROWS * D];  // 16 KB

    const float4* w4 = (const float4*)w;
    float4* wl4 = (float4*)wlds;
    for (int i = threadIdx.x; i < D * D / 4; i += 256) wl4[i] = w4[i];

    int row0 = blockIdx.x * GEMM_ROWS;
    int nrow = n - row0; if (nrow > GEMM_ROWS) nrow = GEMM_ROWS;
    const float4* x4 = (const float4*)(x + (size_t)row0 * D);
    float4* xl4 = (float4*)xlds;
    for (int i = threadIdx.x; i < nrow * D / 4; i += 256) xl4[i] = x4[i];
    __syncthreads();

    int tc = (threadIdx.x & 31) * 4;   // 4 consecutive output cols
    int tr = (threadIdx.x >> 5) * 4;   // 4 rows

    float4 a0 = {0.f,0.f,0.f,0.f}, a1 = a0, a2 = a0, a3 = a0;

    #pragma unroll 8
    for (int k = 0; k < D; ++k) {
        float4 wv = *(const float4*)&wlds[k * D + tc];
        float x0 = xlds[(tr + 0) * D + k];
        float x1 = xlds[(tr + 1) * D + k];
        float x2 = xlds[(tr + 2) * D + k];
        float x3 = xlds[(tr + 3) * D + k];
        a0.x += x0 * wv.x; a0.y += x0 * wv.y; a0.z += x0 * wv.z; a0.w += x0 * wv.w;
        a1.x += x1 * wv.x; a1.y += x1 * wv.y; a1.z += x1 * wv.z; a1.w += x1 * wv.w;
        a2.x += x2 * wv.x; a2.y += x2 * wv.y; a2.z += x2 * wv.z; a2.w += x2 * wv.w;
        a3.x += x3 * wv.x; a3.y += x3 * wv.y; a3.z += x3 * wv.z; a3.w += x3 * wv.w;
    }

    if (row0 + tr + 0 < n) *(float4*)&h[(size_t)(row0 + tr + 0) * D + tc] = a0;
    if (row0 + tr + 1 < n) *(float4*)&h[(size_t)(row0 + tr + 1) * D + tc] = a1;
    if (row0 + tr + 2 < n) *(float4*)&h[(size_t)(row0 + tr + 2) * D + tc] = a2;
    if (row0 + tr + 3 < n) *(float4*)&h[(size_t)(row0 + tr + 3) * D + tc] = a3;
}

// ---------------- degree count ----------------
__global__ __launch_bounds__(256) void count_kernel(const int* __restrict__ row,
                                                    int* __restrict__ deg, int e) {
    int i = blockIdx.x * 256 + threadIdx.x;
    if (i < e) atomicAdd(&deg[row[i]], 1);
}

// ---------------- exclusive scan (single block, 1024 threads) ----------------
// reads degrees from `cursor`, writes exclusive prefix into offs[] and back
// into cursor[] (fill cursor), offs[n] = total.
__global__ __launch_bounds__(1024) void scan_kernel(int* __restrict__ cursor,
                                                    int* __restrict__ offs, int n) {
    __shared__ int wsum[16];
    __shared__ int wpre[16];
    __shared__ int ctot;
    __shared__ int carry;
    if (threadIdx.x == 0) carry = 0;
    __syncthreads();

    int lane = threadIdx.x & 63;
    int wv = threadIdx.x >> 6;

    for (int base = 0; base < n; base += 1024) {
        int i = base + threadIdx.x;
        int v = (i < n) ? cursor[i] : 0;
        int s = v;
        #pragma unroll
        for (int d = 1; d < 64; d <<= 1) {
            int t = __shfl_up(s, d);
            if (lane >= d) s += t;
        }
        if (lane == 63) wsum[wv] = s;
        __syncthreads();                    // B1
        int c = carry;
        if (wv == 0) {
            int xv = (lane < 16) ? wsum[lane] : 0;
            int ss = xv;
            #pragma unroll
            for (int d = 1; d < 16; d <<= 1) {
                int t = __shfl_up(ss, d);
                if (lane >= d) ss += t;
            }
            if (lane < 16) wpre[lane] = ss - xv;   // exclusive wave prefix
            if (lane == 15) ctot = ss;             // chunk total
        }
        __syncthreads();                    // B2
        int excl = c + wpre[wv] + s - v;
        if (i < n) { offs[i] = excl; cursor[i] = excl; }
        if (threadIdx.x == 0) carry = c + ctot;
        __syncthreads();                    // B3
    }
    if (threadIdx.x == 0) offs[n] = carry;
}

// ---------------- bucket fill ----------------
__global__ __launch_bounds__(256) void fill_kernel(const int* __restrict__ row,
                                                   int* __restrict__ cursor,
                                                   int* __restrict__ bucket, int e) {
    int i = blockIdx.x * 256 + threadIdx.x;
    if (i < e) {
        int p = atomicAdd(&cursor[row[i]], 1);
        bucket[p] = i;
    }
}

// ---------------- per-node gather-reduce ----------------
// 128 threads per node (feature t), 2 nodes per 256-thread block.
__global__ __launch_bounds__(256) void reduce_kernel(const float* __restrict__ h,
                                                     const float* __restrict__ ev,
                                                     const int* __restrict__ col,
                                                     const int* __restrict__ offs,
                                                     const int* __restrict__ bucket,
                                                     const float* __restrict__ bias,
                                                     float* __restrict__ out, int n) {
    int node = blockIdx.x * 2 + (threadIdx.x >> 7);
    if (node >= n) return;
    int t = threadIdx.x & 127;
    int beg = offs[node];
    int end = offs[node + 1];
    float acc = 0.f;
    for (int j = beg; j < end; ++j) {
        int e = bucket[j];
        acc += ev[e] * h[(size_t)col[e] * D + t];
    }
    out[(size_t)node * D + t] = acc + bias[t];
}

extern "C" void kernel_launch(void* const* d_in, const int* in_sizes, int n_in,
                              void* d_out, int out_size, void* d_ws, size_t ws_size,
                              hipStream_t stream) {
    const float* x    = (const float*)d_in[0];
    const float* w    = (const float*)d_in[1];
    const float* bias = (const float*)d_in[2];
    const float* ev   = (const float*)d_in[3];
    const int*   row  = (const int*)d_in[4];
    const int*   col  = (const int*)d_in[5];
    float* out = (float*)d_out;

    int n = in_sizes[0] / D;   // 100000
    int e = in_sizes[3];       // 1600000

    // workspace layout
    float* h    = (float*)d_ws;               // n*D floats
    int* offs   = (int*)(h + (size_t)n * D);  // n+1
    int* cursor = offs + (n + 1);             // n
    int* bucket = cursor + n;                 // e

    hipMemsetAsync(cursor, 0, (size_t)n * sizeof(int), stream);

    gemm_kernel<<<(n + GEMM_ROWS - 1) / GEMM_ROWS, 256, 0, stream>>>(x, w, h, n);
    count_kernel<<<(e + 255) / 256, 256, 0, stream>>>(row, cursor, e);
    scan_kernel<<<1, 1024, 0, stream>>>(cursor, offs, n);
    fill_kernel<<<(e + 255) / 256, 256, 0, stream>>>(row, cursor, bucket, e);
    reduce_kernel<<<(n + 1) / 2, 256, 0, stream>>>(h, ev, col, offs, bucket, bias, out, n);
}

// Round 2
// 394.018 us; speedup vs baseline: 1.9999x; 1.9999x over previous
//
#include <hip/hip_runtime.h>

#define D 128
#define GEMM_ROWS 32
#define SCAN_TILE 2048   // 256 threads x 8 elems

// ---------------- GEMM: h = x @ W ----------------
__global__ __launch_bounds__(256) void gemm_kernel(const float* __restrict__ x,
                                                   const float* __restrict__ w,
                                                   float* __restrict__ h, int n) {
    __shared__ float wlds[D * D];          // 64 KB
    __shared__ float xlds[GEMM_ROWS * D];  // 16 KB

    const float4* w4 = (const float4*)w;
    float4* wl4 = (float4*)wlds;
    for (int i = threadIdx.x; i < D * D / 4; i += 256) wl4[i] = w4[i];

    int row0 = blockIdx.x * GEMM_ROWS;
    int nrow = n - row0; if (nrow > GEMM_ROWS) nrow = GEMM_ROWS;
    const float4* x4 = (const float4*)(x + (size_t)row0 * D);
    float4* xl4 = (float4*)xlds;
    for (int i = threadIdx.x; i < nrow * D / 4; i += 256) xl4[i] = x4[i];
    __syncthreads();

    int tc = (threadIdx.x & 31) * 4;
    int tr = (threadIdx.x >> 5) * 4;

    float4 a0 = {0.f,0.f,0.f,0.f}, a1 = a0, a2 = a0, a3 = a0;

    #pragma unroll 8
    for (int k = 0; k < D; ++k) {
        float4 wv = *(const float4*)&wlds[k * D + tc];
        float x0 = xlds[(tr + 0) * D + k];
        float x1 = xlds[(tr + 1) * D + k];
        float x2 = xlds[(tr + 2) * D + k];
        float x3 = xlds[(tr + 3) * D + k];
        a0.x += x0 * wv.x; a0.y += x0 * wv.y; a0.z += x0 * wv.z; a0.w += x0 * wv.w;
        a1.x += x1 * wv.x; a1.y += x1 * wv.y; a1.z += x1 * wv.z; a1.w += x1 * wv.w;
        a2.x += x2 * wv.x; a2.y += x2 * wv.y; a2.z += x2 * wv.z; a2.w += x2 * wv.w;
        a3.x += x3 * wv.x; a3.y += x3 * wv.y; a3.z += x3 * wv.z; a3.w += x3 * wv.w;
    }

    if (row0 + tr + 0 < n) *(float4*)&h[(size_t)(row0 + tr + 0) * D + tc] = a0;
    if (row0 + tr + 1 < n) *(float4*)&h[(size_t)(row0 + tr + 1) * D + tc] = a1;
    if (row0 + tr + 2 < n) *(float4*)&h[(size_t)(row0 + tr + 2) * D + tc] = a2;
    if (row0 + tr + 3 < n) *(float4*)&h[(size_t)(row0 + tr + 3) * D + tc] = a3;
}

// ---------------- degree count (4 edges/thread) ----------------
__global__ __launch_bounds__(256) void count_kernel(const int* __restrict__ row,
                                                    int* __restrict__ deg, int e) {
    int i = (blockIdx.x * 256 + threadIdx.x) * 4;
    if (i + 4 <= e) {
        int4 r = *(const int4*)(row + i);
        atomicAdd(&deg[r.x], 1); atomicAdd(&deg[r.y], 1);
        atomicAdd(&deg[r.z], 1); atomicAdd(&deg[r.w], 1);
    } else {
        for (; i < e; ++i) atomicAdd(&deg[row[i]], 1);
    }
}

// ---------------- 3-phase exclusive scan ----------------
// A: per-block local exclusive scan (2048 elems), block total -> part[]
__global__ __launch_bounds__(256) void scan_a(const int* __restrict__ deg,
                                              int* __restrict__ offs,
                                              int* __restrict__ part, int n) {
    __shared__ int wsum[4];
    int tid = threadIdx.x;
    int lane = tid & 63, wv = tid >> 6;
    int base = blockIdx.x * SCAN_TILE + tid * 8;
    int v[8]; int tsum = 0;
    #pragma unroll
    for (int k = 0; k < 8; ++k) { v[k] = (base + k < n) ? deg[base + k] : 0; tsum += v[k]; }
    int incl = tsum;
    #pragma unroll
    for (int d = 1; d < 64; d <<= 1) { int t = __shfl_up(incl, d); if (lane >= d) incl += t; }
    if (lane == 63) wsum[wv] = incl;
    __syncthreads();
    int wpre = 0;
    #pragma unroll
    for (int w = 0; w < 4; ++w) if (w < wv) wpre += wsum[w];
    int run = wpre + incl - tsum;
    #pragma unroll
    for (int k = 0; k < 8; ++k) { if (base + k < n) offs[base + k] = run; run += v[k]; }
    if (tid == 255) part[blockIdx.x] = wpre + incl;
}

// B: exclusive scan of block partials (1 wave, carry loop), also offs[n]=e
__global__ __launch_bounds__(64) void scan_b(int* __restrict__ part, int nb,
                                             int* __restrict__ offs, int n, int e) {
    int lane = threadIdx.x;
    int carry = 0;
    for (int base = 0; base < nb; base += 64) {
        int i = base + lane;
        int v = (i < nb) ? part[i] : 0;
        int s = v;
        #pragma unroll
        for (int d = 1; d < 64; d <<= 1) { int t = __shfl_up(s, d); if (lane >= d) s += t; }
        if (i < nb) part[i] = carry + s - v;
        carry += __shfl(s, 63);
    }
    if (lane == 0) offs[n] = e;
}

// C: add block offset; write final offs and cursor copy
__global__ __launch_bounds__(256) void scan_c(const int* __restrict__ part,
                                              int* __restrict__ offs,
                                              int* __restrict__ cursor, int n) {
    int add = part[blockIdx.x];
    int base = blockIdx.x * SCAN_TILE + threadIdx.x * 8;
    #pragma unroll
    for (int k = 0; k < 8; ++k) {
        int i = base + k;
        if (i < n) { int f = offs[i] + add; offs[i] = f; cursor[i] = f; }
    }
}

// ---------------- bucket fill: packed (col, val) pairs ----------------
__global__ __launch_bounds__(256) void fill_kernel(const int* __restrict__ row,
                                                   const int* __restrict__ col,
                                                   const float* __restrict__ ev,
                                                   int* __restrict__ cursor,
                                                   int2* __restrict__ pairs, int e) {
    int i = (blockIdx.x * 256 + threadIdx.x) * 4;
    if (i + 4 <= e) {
        int4 r = *(const int4*)(row + i);
        int4 c = *(const int4*)(col + i);
        float4 v = *(const float4*)(ev + i);
        int p;
        p = atomicAdd(&cursor[r.x], 1); pairs[p] = make_int2(c.x, __float_as_int(v.x));
        p = atomicAdd(&cursor[r.y], 1); pairs[p] = make_int2(c.y, __float_as_int(v.y));
        p = atomicAdd(&cursor[r.z], 1); pairs[p] = make_int2(c.z, __float_as_int(v.z));
        p = atomicAdd(&cursor[r.w], 1); pairs[p] = make_int2(c.w, __float_as_int(v.w));
    } else {
        for (; i < e; ++i) {
            int p = atomicAdd(&cursor[row[i]], 1);
            pairs[p] = make_int2(col[i], __float_as_int(ev[i]));
        }
    }
}

// ---------------- per-node gather-reduce ----------------
// one wave (64 lanes) per node, float2 per lane, unroll x4 for 4 h-rows in flight
__global__ __launch_bounds__(256) void reduce_kernel(const float2* __restrict__ hv,
                                                     const int2* __restrict__ pairs,
                                                     const int* __restrict__ offs,
                                                     const float2* __restrict__ bias,
                                                     float2* __restrict__ out, int n) {
    int node = blockIdx.x * 4 + (threadIdx.x >> 6);
    if (node >= n) return;
    int lane = threadIdx.x & 63;
    int beg = offs[node];
    int end = offs[node + 1];
    float2 acc = {0.f, 0.f};
    int j = beg;
    for (; j + 4 <= end; j += 4) {
        int2 p0 = pairs[j + 0];
        int2 p1 = pairs[j + 1];
        int2 p2 = pairs[j + 2];
        int2 p3 = pairs[j + 3];
        float2 r0 = hv[(size_t)p0.x * 64 + lane];
        float2 r1 = hv[(size_t)p1.x * 64 + lane];
        float2 r2 = hv[(size_t)p2.x * 64 + lane];
        float2 r3 = hv[(size_t)p3.x * 64 + lane];
        float v0 = __int_as_float(p0.y), v1 = __int_as_float(p1.y);
        float v2 = __int_as_float(p2.y), v3 = __int_as_float(p3.y);
        acc.x += v0 * r0.x; acc.y += v0 * r0.y;
        acc.x += v1 * r1.x; acc.y += v1 * r1.y;
        acc.x += v2 * r2.x; acc.y += v2 * r2.y;
        acc.x += v3 * r3.x; acc.y += v3 * r3.y;
    }
    for (; j < end; ++j) {
        int2 p = pairs[j];
        float2 r = hv[(size_t)p.x * 64 + lane];
        float v = __int_as_float(p.y);
        acc.x += v * r.x; acc.y += v * r.y;
    }
    float2 b = bias[lane];
    out[(size_t)node * 64 + lane] = make_float2(acc.x + b.x, acc.y + b.y);
}

extern "C" void kernel_launch(void* const* d_in, const int* in_sizes, int n_in,
                              void* d_out, int out_size, void* d_ws, size_t ws_size,
                              hipStream_t stream) {
    const float* x    = (const float*)d_in[0];
    const float* w    = (const float*)d_in[1];
    const float* bias = (const float*)d_in[2];
    const float* ev   = (const float*)d_in[3];
    const int*   row  = (const int*)d_in[4];
    const int*   col  = (const int*)d_in[5];
    float* out = (float*)d_out;

    int n = in_sizes[0] / D;   // 100000
    int e = in_sizes[3];       // 1600000
    int nb = (n + SCAN_TILE - 1) / SCAN_TILE;

    // workspace layout (8B-aligned segments)
    float* h     = (float*)d_ws;                        // n*D floats (51.2 MB)
    int2*  pairs = (int2*)(h + (size_t)n * D);          // e int2 (12.8 MB)
    int*   offs  = (int*)(pairs + e);                   // n+1
    int*   cursor= offs + (n + 1);                      // n
    int*   part  = cursor + n;                          // nb

    hipMemsetAsync(cursor, 0, (size_t)n * sizeof(int), stream);

    gemm_kernel<<<(n + GEMM_ROWS - 1) / GEMM_ROWS, 256, 0, stream>>>(x, w, h, n);
    count_kernel<<<(e + 1023) / 1024, 256, 0, stream>>>(row, cursor, e);
    scan_a<<<nb, 256, 0, stream>>>(cursor, offs, part, n);
    scan_b<<<1, 64, 0, stream>>>(part, nb, offs, n, e);
    scan_c<<<nb, 256, 0, stream>>>(part, offs, cursor, n);
    fill_kernel<<<(e + 1023) / 1024, 256, 0, stream>>>(row, col, ev, cursor, pairs, e);
    reduce_kernel<<<(n + 3) / 4, 256, 0, stream>>>((const float2*)h, pairs, offs,
                                                   (const float2*)bias, (float2*)out, n);
}